// Round 8
// baseline (1147.240 us; speedup 1.0000x reference)
//
#include <hip/hip_runtime.h>
#include <hip/hip_bf16.h>
#include <math.h>

typedef __attribute__((ext_vector_type(8))) short bf16x8;
typedef __attribute__((ext_vector_type(4))) float f32x4;

static __device__ __forceinline__ unsigned short f2bf(float f) {
    union { float f; unsigned u; } v; v.f = f;
    unsigned r = v.u + 0x7fffu + ((v.u >> 16) & 1u);
    return (unsigned short)(r >> 16);
}

#define GLOAD16(g, l) __builtin_amdgcn_global_load_lds( \
    (const __attribute__((address_space(1))) void*)(g), \
    (__attribute__((address_space(3))) void*)(l), 16, 0, 0)

// ---------------- fp8 e4m3 (OCP) helpers: HW cvt if available ---------------
#if defined(__has_builtin)
#  if __has_builtin(__builtin_amdgcn_cvt_pk_fp8_f32) && __has_builtin(__builtin_amdgcn_cvt_pk_f32_fp8)
#    define HAVE_FP8_CVT 1
#  endif
#endif
#ifndef HAVE_FP8_CVT
#  define HAVE_FP8_CVT 0
#endif

static __device__ __forceinline__ float f8dec_sw(unsigned b) {
    unsigned s = b >> 7, e = (b >> 3) & 15, m = b & 7;
    float v = e ? ldexpf((float)(8 + m), (int)e - 10) : ldexpf((float)m, -9);
    return s ? -v : v;
}
static __device__ __forceinline__ unsigned char f8enc_sw(float x) {
    union { float f; unsigned u; } v; v.f = x;
    unsigned s = (v.u >> 31) << 7;
    float ax = fabsf(x);
    if (ax >= 448.f) return (unsigned char)(s | 0x7E);
    if (ax < 0.015625f) { int m = (int)(ax * 512.f + 0.5f); return (unsigned char)(s | m); }
    int e; float fr = frexpf(ax, &e);
    int q = (int)(fr * 16.f + 0.5f);
    if (q == 16) { q = 8; e += 1; }
    if (e - 1 > 8) return (unsigned char)(s | 0x7E);
    return (unsigned char)(s | ((e - 1 + 7) << 3) | (q - 8));
}
static __device__ __forceinline__ unsigned char f8e(float v) {
#if HAVE_FP8_CVT
    return (unsigned char)(__builtin_amdgcn_cvt_pk_fp8_f32(v, v, 0, false) & 0xFF);
#else
    return f8enc_sw(v);
#endif
}
static __device__ __forceinline__ void f8d2_lo(unsigned w, float& x, float& y) {
#if HAVE_FP8_CVT
    auto r = __builtin_amdgcn_cvt_pk_f32_fp8((int)w, false);
    x = r[0]; y = r[1];
#else
    x = f8dec_sw(w & 0xFF); y = f8dec_sw((w >> 8) & 0xFF);
#endif
}
static __device__ __forceinline__ void f8d2_hi(unsigned w, float& x, float& y) {
#if HAVE_FP8_CVT
    auto r = __builtin_amdgcn_cvt_pk_f32_fp8((int)w, true);
    x = r[0]; y = r[1];
#else
    x = f8dec_sw((w >> 16) & 0xFF); y = f8dec_sw((w >> 24) & 0xFF);
#endif
}

// ---------------------------------------------------------------------------
// Weight conversion (unchanged layouts).
// WcT: plane-major dst[((k>>3)*256 + n)*8 + (k&7)], K=512 (vv|vc), N=256.
// WgT: K=256, N=1536 = [W1a(512) | W1b(512) | uW1(512)]
// ---------------------------------------------------------------------------
__global__ __launch_bounds__(256) void conv_weights(
    const float* __restrict__ Wvv, const float* __restrict__ Wvc,
    const float* __restrict__ bW1, const float* __restrict__ uW1,
    unsigned short* __restrict__ WcT, unsigned short* __restrict__ WgT)
{
    int idx = blockIdx.x * 256 + threadIdx.x;
    if (idx < 131072) {                       // WcT
        int n = idx & 255, k = idx >> 8;
        float s = (k < 256) ? Wvv[k * 256 + n] : Wvc[(k - 256) * 256 + n];
        WcT[((k >> 3) * 256 + n) * 8 + (k & 7)] = f2bf(s);
    } else {                                  // WgT: 393216 elems
        int t = idx - 131072;
        int k = t / 1536, n2 = t - k * 1536;
        float s;
        if (n2 < 512)       s = bW1[k * 512 + n2];
        else if (n2 < 1024) s = bW1[(256 + k) * 512 + (n2 - 512)];
        else                s = uW1[k * 512 + (n2 - 1024)];
        WgT[((k >> 3) * 1536 + n2) * 8 + (k & 7)] = f2bf(s);
    }
}

// ---------------------------------------------------------------------------
// Counting-sort of atoms by mol_id.
// ---------------------------------------------------------------------------
__global__ __launch_bounds__(256) void hist_kernel(
    const int* __restrict__ mol_id, int* __restrict__ bins, int NA)
{
    int i = blockIdx.x * 256 + threadIdx.x;
    if (i < NA) atomicAdd(&bins[mol_id[i]], 1);
}

__global__ __launch_bounds__(1024) void scan_kernel(
    const int* __restrict__ bins, int* __restrict__ offs,
    int* __restrict__ cursor, int NM)
{
    __shared__ int buf[1024];
    const int t = threadIdx.x;
    int base = 0;
    for (int c0 = 0; c0 < NM; c0 += 1024) {
        int v = (c0 + t < NM) ? bins[c0 + t] : 0;
        buf[t] = v;
        __syncthreads();
        for (int d = 1; d < 1024; d <<= 1) {
            int x = (t >= d) ? buf[t - d] : 0;
            __syncthreads();
            buf[t] += x;
            __syncthreads();
        }
        int incl = buf[t];
        if (c0 + t < NM) {
            int ex = base + incl - v;
            offs[c0 + t] = ex;
            cursor[c0 + t] = ex;
        }
        int tot = buf[1023];
        __syncthreads();
        base += tot;
    }
    if (t == 0) offs[NM] = base;
}

__global__ __launch_bounds__(256) void scatter_kernel(
    const int* __restrict__ mol_id, int* __restrict__ cursor,
    int* __restrict__ sorted, int NA)
{
    int i = blockIdx.x * 256 + threadIdx.x;
    if (i < NA) {
        int p = atomicAdd(&cursor[mol_id[i]], 1);
        sorted[p] = i;
    }
}

// hm[mol] = sum of haB rows of that mol (fp32 accum, zero atomics).
__global__ __launch_bounds__(256) void hm_kernel(
    const unsigned short* __restrict__ haB, const int* __restrict__ sorted,
    const int* __restrict__ offs, float* __restrict__ hm, int NM)
{
    __shared__ float red[256][2];
    const int mol = blockIdx.x;
    const int t = threadIdx.x;
    const int sub = t >> 7, cp = t & 127;
    const int s0 = offs[mol], s1 = offs[mol + 1];
    float a0 = 0.f, a1 = 0.f;
    for (int i = s0 + sub; i < s1; i += 2) {
        int a = sorted[i];
        unsigned w = *(const unsigned*)(haB + (size_t)a * 256 + cp * 2);
        union { unsigned u; float f; } lo, hi;
        lo.u = w << 16;
        hi.u = w & 0xFFFF0000u;
        a0 += lo.f;
        a1 += hi.f;
    }
    red[t][0] = a0; red[t][1] = a1;
    __syncthreads();
    if (t < 128) {
        float r0 = red[t][0] + red[t + 128][0];
        float r1 = red[t][1] + red[t + 128][1];
        float2* dst = (float2*)&hm[(size_t)mol * 256 + cp * 2];
        *dst = make_float2(r0, r1);
    }
}

// ---------------------------------------------------------------------------
// FUSED: phase1 ha = relu(ha_prev@Wvv + c_atom@Wvc), ha[0]=0 -> haB + LDS tile
//        phase2 [Ga|Gb] fp8 + uni logits, K=256 from LDS, B from L2.
// BM=128, 8 waves. LDS: As[4][128][64] (64KB; planes double as phase1 dbuf).
// ---------------------------------------------------------------------------
__global__ __launch_bounds__(512, 4) void fused_kernel(
    const float* __restrict__ ha_prev, const float* __restrict__ c_atom,
    const unsigned short* __restrict__ WcT, const unsigned short* __restrict__ WgT,
    unsigned short* __restrict__ haB, unsigned char* __restrict__ G,
    float* __restrict__ outU, const float* __restrict__ ub1,
    const float* __restrict__ uW2, const float* __restrict__ ub2,
    int NA, int doG)
{
    __shared__ __align__(16) unsigned short As[4][128][64];   // 64 KB
    __shared__ float obuf[128];

    const int tid = threadIdx.x;
    const int wv = tid >> 6, lane = tid & 63;
    const int wr = wv >> 2, wc = wv & 3;
    const int c15 = lane & 15, kq = lane >> 4;
    const int xm3 = (c15 & 7) << 3;
    const int m0 = blockIdx.x * 128;

    // ---------------- phase 1: ha GEMM (K=512, N=256) ----------------
    const int cr0 = tid >> 3, chc = tid & 7;
    const int cr1 = (512 + tid) >> 3;
    int row0 = m0 + cr0; if (row0 >= NA) row0 = NA - 1;
    int row1 = m0 + cr1; if (row1 >= NA) row1 = NA - 1;

    f32x4 v00, v01, v10, v11;
    #define HA_LOAD(ks) { \
        const float* src = ((ks) < 4) ? ha_prev : c_atom; \
        const int kb = ((ks) & 3) * 64 + chc * 8; \
        const float* s0 = src + (size_t)row0 * 256 + kb; \
        const float* s1 = src + (size_t)row1 * 256 + kb; \
        v00 = *(const f32x4*)s0; v01 = *(const f32x4*)(s0 + 4); \
        v10 = *(const f32x4*)s1; v11 = *(const f32x4*)(s1 + 4); }
    #define HA_WRITE(buf) { \
        bf16x8 p0, p1; \
        p0[0]=(short)f2bf(v00[0]); p0[1]=(short)f2bf(v00[1]); p0[2]=(short)f2bf(v00[2]); p0[3]=(short)f2bf(v00[3]); \
        p0[4]=(short)f2bf(v01[0]); p0[5]=(short)f2bf(v01[1]); p0[6]=(short)f2bf(v01[2]); p0[7]=(short)f2bf(v01[3]); \
        p1[0]=(short)f2bf(v10[0]); p1[1]=(short)f2bf(v10[1]); p1[2]=(short)f2bf(v10[2]); p1[3]=(short)f2bf(v10[3]); \
        p1[4]=(short)f2bf(v11[0]); p1[5]=(short)f2bf(v11[1]); p1[6]=(short)f2bf(v11[2]); p1[7]=(short)f2bf(v11[3]); \
        *(bf16x8*)&As[buf][cr0][(chc * 8) ^ ((cr0 & 7) << 3)] = p0; \
        *(bf16x8*)&As[buf][cr1][(chc * 8) ^ ((cr1 & 7) << 3)] = p1; }

    f32x4 acc[4][4];
#pragma unroll
    for (int m = 0; m < 4; ++m)
#pragma unroll
        for (int n = 0; n < 4; ++n) acc[m][n] = (f32x4){0.f, 0.f, 0.f, 0.f};

    HA_LOAD(0); HA_WRITE(0);
    __syncthreads();

    for (int ks = 0; ks < 8; ++ks) {
        if (ks < 7) HA_LOAD(ks + 1);
        const int buf = ks & 1;
#pragma unroll
        for (int kk = 0; kk < 2; ++kk) {
            bf16x8 aF[4], bF[4];
            const int plane = ks * 8 + kk * 4 + kq;
#pragma unroll
            for (int n = 0; n < 4; ++n)
                bF[n] = *(const bf16x8*)(WcT + ((size_t)plane * 256 + wc * 64 + n * 16 + c15) * 8);
#pragma unroll
            for (int m = 0; m < 4; ++m)
                aF[m] = *(const bf16x8*)&As[buf][wr * 64 + m * 16 + c15][(kk * 32 + kq * 8) ^ xm3];
#pragma unroll
            for (int m = 0; m < 4; ++m)
#pragma unroll
                for (int n = 0; n < 4; ++n)
                    acc[m][n] = __builtin_amdgcn_mfma_f32_16x16x32_bf16(aF[m], bF[n], acc[m][n], 0, 0, 0);
        }
        if (ks < 7) HA_WRITE((ks + 1) & 1);
        __syncthreads();
    }

    // phase-1 epilogue: relu, zero row0, write haB; deposit tile into LDS
    // (dbuf is dead: last __syncthreads ensures all waves finished reads)
    if (tid < 128) obuf[tid] = 0.f;
#pragma unroll
    for (int m = 0; m < 4; ++m) {
#pragma unroll
        for (int reg = 0; reg < 4; ++reg) {
            int rl = wr * 64 + m * 16 + kq * 4 + reg;
            int row = m0 + rl;
            bool z = (row == 0);
            bool ok = (row < NA);
#pragma unroll
            for (int n = 0; n < 4; ++n) {
                int col = wc * 64 + n * 16 + c15;
                float v = fmaxf(acc[m][n][reg], 0.f);
                if (z) v = 0.f;
                unsigned short bv = f2bf(v);
                if (ok) haB[(size_t)row * 256 + col] = bv;
                // LDS tile: plane col>>6(==wc), elem (rl, col&63), XOR swizzle
                As[wc][rl][(((col >> 3) & 7) ^ (rl & 7)) * 8 + (col & 7)] = bv;
            }
        }
    }
    if (!doG) return;
    __syncthreads();

    // ---------------- phase 2: [Ga|Gb|uni] (K=256 from LDS) ----------------
    const int rg = wv >> 2, cg = wv & 3;    // 2 row-groups x 4 col-groups(128)
    for (int nbc = 0; nbc < 3; ++nbc) {
#pragma unroll
        for (int nt = 0; nt < 2; ++nt) {
            const int colbase = nbc * 512 + cg * 128 + nt * 64;
            f32x4 a2[4][4];
#pragma unroll
            for (int m = 0; m < 4; ++m)
#pragma unroll
                for (int n = 0; n < 4; ++n) a2[m][n] = (f32x4){0.f, 0.f, 0.f, 0.f};

            bf16x8 br[2][4];
#pragma unroll
            for (int n = 0; n < 4; ++n)
                br[0][n] = *(const bf16x8*)(WgT + ((size_t)kq * 1536 + colbase + n * 16 + c15) * 8);
#pragma unroll
            for (int s = 0; s < 8; ++s) {
                if (s < 7) {
                    const int pl = (s + 1) * 4 + kq;
#pragma unroll
                    for (int n = 0; n < 4; ++n)
                        br[(s + 1) & 1][n] = *(const bf16x8*)(WgT + ((size_t)pl * 1536 + colbase + n * 16 + c15) * 8);
                }
                const int kt = s >> 1, kk = s & 1;
                bf16x8 aF[4];
#pragma unroll
                for (int m = 0; m < 4; ++m) {
                    int r = rg * 64 + m * 16 + c15;
                    aF[m] = *(const bf16x8*)&As[kt][r][((kk * 4 + kq) ^ (r & 7)) * 8];
                }
#pragma unroll
                for (int m = 0; m < 4; ++m)
#pragma unroll
                    for (int n = 0; n < 4; ++n)
                        a2[m][n] = __builtin_amdgcn_mfma_f32_16x16x32_bf16(aF[m], br[s & 1][n], a2[m][n], 0, 0, 0);
            }

            if (nbc < 2) {
                // fp8 G writes
#pragma unroll
                for (int m = 0; m < 4; ++m) {
#pragma unroll
                    for (int reg = 0; reg < 4; ++reg) {
                        int row = m0 + rg * 64 + m * 16 + kq * 4 + reg;
                        if (row >= NA) continue;
#pragma unroll
                        for (int n = 0; n < 4; ++n) {
                            int col = cg * 128 + nt * 64 + n * 16 + c15;
                            G[(size_t)row * 1024 + nbc * 512 + col] = f8e(a2[m][n][reg]);
                        }
                    }
                }
            } else {
                // uni: relu(h + ub1) @ uW2, reduce over this wave's 64 cols
                float b1c[4], w2c[4];
#pragma unroll
                for (int n = 0; n < 4; ++n) {
                    int col = cg * 128 + nt * 64 + n * 16 + c15;
                    b1c[n] = ub1[col];
                    w2c[n] = uW2[col];
                }
#pragma unroll
                for (int m = 0; m < 4; ++m) {
#pragma unroll
                    for (int reg = 0; reg < 4; ++reg) {
                        float s0 = 0.f;
#pragma unroll
                        for (int n = 0; n < 4; ++n)
                            s0 += fmaxf(a2[m][n][reg] + b1c[n], 0.f) * w2c[n];
#pragma unroll
                        for (int off = 1; off < 16; off <<= 1) s0 += __shfl_xor(s0, off);
                        if (c15 == 0)
                            atomicAdd(&obuf[rg * 64 + m * 16 + kq * 4 + reg], s0);
                    }
                }
            }
        }
    }
    __syncthreads();
    if (tid < 128) {
        int row = m0 + tid;
        if (row < NA) outU[row] = obuf[tid] + ub2[0];
    }
}

// ---------------------------------------------------------------------------
// bond_stream: out[e] = relu(Ga[b0] + Gb[b1] + b1) @ W2 + b2.
// ---------------------------------------------------------------------------
__global__ __launch_bounds__(256) void bond_stream(
    const unsigned char* __restrict__ G, const int* __restrict__ bidx,
    const float* __restrict__ b1, const float* __restrict__ W2,
    const float* __restrict__ b2, float* __restrict__ outB, int NB, int nwaves)
{
    const int lane = threadIdx.x & 63;
    const int wid = (blockIdx.x * blockDim.x + threadIdx.x) >> 6;

    float b1c[8], w2c[8][5];
#pragma unroll
    for (int i = 0; i < 8; ++i) {
        int h = lane * 8 + i;
        b1c[i] = b1[h];
#pragma unroll
        for (int j = 0; j < 5; ++j) w2c[i][j] = W2[h * 5 + j];
    }
    float bb[5];
#pragma unroll
    for (int j = 0; j < 5; ++j) bb[j] = b2[j];

    int e = wid;
    if (e >= NB) return;
    int2 ep = ((const int2*)bidx)[e];
    int2 epN = (e + nwaves < NB) ? ((const int2*)bidx)[e + nwaves] : ep;
    uint2 ga = *(const uint2*)(G + (size_t)ep.x * 1024 + lane * 8);
    uint2 gb = *(const uint2*)(G + (size_t)ep.y * 1024 + 512 + lane * 8);

    while (e < NB) {
        int en = e + nwaves;
        uint2 gaN, gbN; int2 epN2 = epN;
        if (en < NB) {
            gaN = *(const uint2*)(G + (size_t)epN.x * 1024 + lane * 8);
            gbN = *(const uint2*)(G + (size_t)epN.y * 1024 + 512 + lane * 8);
            int e2 = en + nwaves;
            if (e2 < NB) epN2 = ((const int2*)bidx)[e2];
        }
        float s[5] = {0.f, 0.f, 0.f, 0.f, 0.f};
#pragma unroll
        for (int half = 0; half < 2; ++half) {
            unsigned wa = half ? ga.y : ga.x;
            unsigned wb = half ? gb.y : gb.x;
            float a0v, a1v, a2v, a3v, b0v, b1v, b2v, b3v;
            f8d2_lo(wa, a0v, a1v); f8d2_hi(wa, a2v, a3v);
            f8d2_lo(wb, b0v, b1v); f8d2_hi(wb, b2v, b3v);
            float hv[4] = { a0v + b0v, a1v + b1v, a2v + b2v, a3v + b3v };
#pragma unroll
            for (int t = 0; t < 4; ++t) {
                int i = half * 4 + t;
                float p = fmaxf(hv[t] + b1c[i], 0.f);
#pragma unroll
                for (int j = 0; j < 5; ++j) s[j] += p * w2c[i][j];
            }
        }
#pragma unroll
        for (int off = 1; off < 64; off <<= 1)
#pragma unroll
            for (int j = 0; j < 5; ++j) s[j] += __shfl_xor(s[j], off);
        if (lane == 0) {
#pragma unroll
            for (int j = 0; j < 5; ++j) outB[(size_t)e * 5 + j] = s[j] + bb[j];
        }
        e = en; ga = gaN; gb = gbN; epN = epN2;
    }
}

// ---------------------------------------------------------------------------
// FALLBACK (small ws): fused bond GEMM on WgT layout.
// ---------------------------------------------------------------------------
__global__ __launch_bounds__(512, 4) void bond_gemm(
    const unsigned short* __restrict__ haB, const int* __restrict__ bidx,
    const unsigned short* __restrict__ WgT, const float* __restrict__ b1,
    const float* __restrict__ W2, const float* __restrict__ b2,
    float* __restrict__ outB, int NB)
{
    __shared__ __align__(16) unsigned short As[8 * 64 * 64];
    __shared__ float obuf[64][5];

    const int tid = threadIdx.x;
    const int wv = tid >> 6, lane = tid & 63;
    const int c15 = lane & 15, kq = lane >> 4;
    const int b0 = blockIdx.x * 64;

    if (tid < 320) ((float*)obuf)[tid] = 0.f;

    {
        const int ep = wv >> 2, koff = (wv & 3) * 64;
        const int rsub = lane >> 3, csub = lane & 7;
        int eidxs[8];
#pragma unroll
        for (int j = 0; j < 8; ++j) {
            int gbd = b0 + j * 8 + rsub; if (gbd >= NB) gbd = 0;
            eidxs[j] = bidx[gbd * 2 + ep];
        }
#pragma unroll
        for (int j = 0; j < 8; ++j) {
            int r = j * 8 + rsub;
            GLOAD16(haB + (size_t)eidxs[j] * 256 + koff + (size_t)((csub ^ (r & 7)) * 8),
                    As + wv * 4096 + j * 512);
        }
    }
    __syncthreads();

    f32x4 acc[4][4];
#pragma unroll
    for (int m = 0; m < 4; ++m)
#pragma unroll
        for (int n = 0; n < 4; ++n) acc[m][n] = (f32x4){0.f, 0.f, 0.f, 0.f};

    bf16x8 breg[2][4];
#pragma unroll
    for (int n = 0; n < 4; ++n)
        breg[0][n] = *(const bf16x8*)(WgT + ((size_t)(kq & 31) * 1536 + (kq >> 5) * 512 + wv * 64 + n * 16 + c15) * 8);
#pragma unroll
    for (int s = 0; s < 16; ++s) {
        if (s < 15) {
            const int pl = (s + 1) * 4 + kq;
#pragma unroll
            for (int n = 0; n < 4; ++n)
                breg[(s + 1) & 1][n] = *(const bf16x8*)(WgT + ((size_t)(pl & 31) * 1536 + (pl >> 5) * 512 + wv * 64 + n * 16 + c15) * 8);
        }
        const int ks = s >> 1, kk = s & 1;
        bf16x8 aF[4];
#pragma unroll
        for (int m = 0; m < 4; ++m) {
            int r = m * 16 + c15;
            aF[m] = *(const bf16x8*)&As[ks * 4096 + r * 64 + (((kk * 4 + kq) ^ (r & 7)) * 8)];
        }
#pragma unroll
        for (int m = 0; m < 4; ++m)
#pragma unroll
            for (int n = 0; n < 4; ++n)
                acc[m][n] = __builtin_amdgcn_mfma_f32_16x16x32_bf16(aF[m], breg[s & 1][n], acc[m][n], 0, 0, 0);
    }

    float b1c[4], w2c[4][5];
#pragma unroll
    for (int n = 0; n < 4; ++n) {
        int col = wv * 64 + n * 16 + c15;
        b1c[n] = b1[col];
#pragma unroll
        for (int j = 0; j < 5; ++j) w2c[n][j] = W2[col * 5 + j];
    }
#pragma unroll
    for (int m = 0; m < 4; ++m) {
#pragma unroll
        for (int reg = 0; reg < 4; ++reg) {
            float s[5] = {0.f, 0.f, 0.f, 0.f, 0.f};
#pragma unroll
            for (int n = 0; n < 4; ++n) {
                float p = fmaxf(acc[m][n][reg] + b1c[n], 0.f);
#pragma unroll
                for (int j = 0; j < 5; ++j) s[j] += p * w2c[n][j];
            }
#pragma unroll
            for (int off = 1; off < 16; off <<= 1)
#pragma unroll
                for (int j = 0; j < 5; ++j) s[j] += __shfl_xor(s[j], off);
            if (c15 == 0) {
                int rl = m * 16 + kq * 4 + reg;
#pragma unroll
                for (int j = 0; j < 5; ++j) atomicAdd(&obuf[rl][j], s[j]);
            }
        }
    }
    __syncthreads();
    {
        int r = tid >> 3, j = tid & 7;
        if (j < 5) {
            int row = b0 + r;
            if (row < NB) outB[(size_t)row * 5 + j] = obuf[r][j] + b2[j];
        }
    }
}

// ---------------------------------------------------------------------------
// FALLBACK uni GEMM, B = WgT cols 1024..1535 (stride 1536).
// ---------------------------------------------------------------------------
__global__ __launch_bounds__(512, 4) void uni_kernel(
    const unsigned short* __restrict__ haB, const unsigned short* __restrict__ WgT,
    const float* __restrict__ b1, const float* __restrict__ W2,
    const float* __restrict__ b2, float* __restrict__ outU, int NA)
{
    __shared__ __align__(16) unsigned short As[4 * 64 * 64];
    __shared__ float obuf[64];

    const int tid = threadIdx.x;
    const int wv = tid >> 6, lane = tid & 63;
    const int c15 = lane & 15, kq = lane >> 4;
    const int a0 = blockIdx.x * 64;

    if (tid < 64) obuf[tid] = 0.f;

    {
        const int kt = wv >> 1, koff = kt * 64;
        const int rsub = lane >> 3, csub = lane & 7;
#pragma unroll
        for (int jj = 0; jj < 4; ++jj) {
            int j = (wv & 1) * 4 + jj;
            int r = j * 8 + rsub;
            int ga = a0 + r; if (ga >= NA) ga = NA - 1;
            GLOAD16(haB + (size_t)ga * 256 + koff + (size_t)((csub ^ (r & 7)) * 8),
                    As + kt * 4096 + j * 512);
        }
    }
    __syncthreads();

    f32x4 acc[4][4];
#pragma unroll
    for (int m = 0; m < 4; ++m)
#pragma unroll
        for (int n = 0; n < 4; ++n) acc[m][n] = (f32x4){0.f, 0.f, 0.f, 0.f};

    bf16x8 breg[2][4];
#pragma unroll
    for (int n = 0; n < 4; ++n)
        breg[0][n] = *(const bf16x8*)(WgT + ((size_t)kq * 1536 + 1024 + wv * 64 + n * 16 + c15) * 8);
#pragma unroll
    for (int s = 0; s < 8; ++s) {
        if (s < 7) {
            const int pl = (s + 1) * 4 + kq;
#pragma unroll
            for (int n = 0; n < 4; ++n)
                breg[(s + 1) & 1][n] = *(const bf16x8*)(WgT + ((size_t)pl * 1536 + 1024 + wv * 64 + n * 16 + c15) * 8);
        }
        const int ks = s >> 1, kk = s & 1;
        bf16x8 aF[4];
#pragma unroll
        for (int m = 0; m < 4; ++m) {
            int r = m * 16 + c15;
            aF[m] = *(const bf16x8*)&As[ks * 4096 + r * 64 + (((kk * 4 + kq) ^ (r & 7)) * 8)];
        }
#pragma unroll
        for (int m = 0; m < 4; ++m)
#pragma unroll
            for (int n = 0; n < 4; ++n)
                acc[m][n] = __builtin_amdgcn_mfma_f32_16x16x32_bf16(acc[m][n] = acc[m][n], breg[s & 1][n], acc[m][n], 0, 0, 0);
    }

    float b1c[4], w2c[4];
#pragma unroll
    for (int n = 0; n < 4; ++n) {
        int col = wv * 64 + n * 16 + c15;
        b1c[n] = b1[col];
        w2c[n] = W2[col];
    }
#pragma unroll
    for (int m = 0; m < 4; ++m) {
#pragma unroll
        for (int reg = 0; reg < 4; ++reg) {
            float s = 0.f;
#pragma unroll
            for (int n = 0; n < 4; ++n)
                s += fmaxf(acc[m][n][reg] + b1c[n], 0.f) * w2c[n];
#pragma unroll
            for (int off = 1; off < 16; off <<= 1) s += __shfl_xor(s, off);
            if (c15 == 0) atomicAdd(&obuf[m * 16 + kq * 4 + reg], s);
        }
    }
    __syncthreads();
    if (tid < 64) {
        int row = a0 + tid;
        if (row < NA) outU[row] = obuf[tid] + b2[0];
    }
}

// ---------------------------------------------------------------------------
// done_logits: 4 molecules per block, fp32 (unchanged)
// ---------------------------------------------------------------------------
__global__ __launch_bounds__(256) void done_kernel(
    const float* __restrict__ hm, const float* __restrict__ W1,
    const float* __restrict__ b1, const float* __restrict__ W2,
    const float* __restrict__ b2, float* __restrict__ outD, int NM)
{
    __shared__ float rsh[4][256];
    __shared__ float red[4][4];
    const int tid = threadIdx.x;
    const int wv = tid >> 6, lane = tid & 63;
    const int mol0 = blockIdx.x * 4;
#pragma unroll
    for (int q = 0; q < 4; ++q)
        rsh[q][tid] = (mol0 + q < NM) ? hm[(size_t)(mol0 + q) * 256 + tid] : 0.f;
    __syncthreads();
    float h[4][2];
#pragma unroll
    for (int q = 0; q < 4; ++q) { h[q][0] = 0.f; h[q][1] = 0.f; }
    for (int k = 0; k < 256; ++k) {
        float w0 = W1[k * 512 + tid];
        float w1 = W1[k * 512 + tid + 256];
#pragma unroll
        for (int q = 0; q < 4; ++q) {
            h[q][0] += rsh[q][k] * w0;
            h[q][1] += rsh[q][k] * w1;
        }
    }
    float bb0 = b1[tid], bb1v = b1[tid + 256];
    float ww0 = W2[tid], ww1 = W2[tid + 256];
#pragma unroll
    for (int q = 0; q < 4; ++q) {
        float p = fmaxf(h[q][0] + bb0, 0.f) * ww0 + fmaxf(h[q][1] + bb1v, 0.f) * ww1;
#pragma unroll
        for (int off = 1; off < 64; off <<= 1) p += __shfl_xor(p, off);
        if (lane == 0) red[q][wv] = p;
    }
    __syncthreads();
    if (tid < 4 && mol0 + tid < NM)
        outD[mol0 + tid] = red[tid][0] + red[tid][1] + red[tid][2] + red[tid][3] + b2[0];
}

// ---------------------------------------------------------------------------
extern "C" void kernel_launch(void* const* d_in, const int* in_sizes, int n_in,
                              void* d_out, int out_size, void* d_ws, size_t ws_size,
                              hipStream_t stream)
{
    const float* c_atom  = (const float*)d_in[0];
    const float* ha_prev = (const float*)d_in[1];
    const float* W_vv    = (const float*)d_in[2];
    const float* W_vc    = (const float*)d_in[3];
    const float* bW1     = (const float*)d_in[4];
    const float* bb1     = (const float*)d_in[5];
    const float* bW2     = (const float*)d_in[6];
    const float* bb2     = (const float*)d_in[7];
    const float* uW1     = (const float*)d_in[8];
    const float* ub1     = (const float*)d_in[9];
    const float* uW2     = (const float*)d_in[10];
    const float* ub2     = (const float*)d_in[11];
    const float* dW1     = (const float*)d_in[12];
    const float* db1     = (const float*)d_in[13];
    const float* dW2     = (const float*)d_in[14];
    const float* db2     = (const float*)d_in[15];
    const int* mol_id    = (const int*)d_in[16];
    const int* bidx      = (const int*)d_in[17];

    const int H = 256, BS = 5;
    const int NA = in_sizes[0] / H;
    const int NB = in_sizes[17] / 2;
    const int NM = out_size - NB * BS - NA;

    float* out  = (float*)d_out;
    float* outB = out;
    float* outU = out + (size_t)NB * BS;
    float* outD = outU + NA;

    char* ws = (char*)d_ws;
    size_t off = 0;
    unsigned short* haB = (unsigned short*)(ws + off);
    off += (size_t)NA * H * 2;            off = (off + 255) & ~(size_t)255;
    float* hm = (float*)(ws + off);
    off += (size_t)NM * H * 4;            off = (off + 255) & ~(size_t)255;
    unsigned short* WcT = (unsigned short*)(ws + off);
    off += (size_t)131072 * 2;            off = (off + 255) & ~(size_t)255;
    unsigned short* WgT = (unsigned short*)(ws + off);
    off += (size_t)393216 * 2;            off = (off + 255) & ~(size_t)255;
    int* bins = (int*)(ws + off);
    off += (size_t)NM * 4;                off = (off + 255) & ~(size_t)255;
    int* cursor = (int*)(ws + off);
    off += (size_t)NM * 4;                off = (off + 255) & ~(size_t)255;
    int* offs = (int*)(ws + off);
    off += (size_t)(NM + 1) * 4;          off = (off + 255) & ~(size_t)255;
    int* sorted = (int*)(ws + off);
    off += (size_t)NA * 4;                off = (off + 255) & ~(size_t)255;
    unsigned char* G = (unsigned char*)(ws + off);
    size_t need_G = off + (size_t)NA * 1024;

    const bool hasG = ws_size >= need_G;

    hipMemsetAsync(bins, 0, (size_t)NM * 4, stream);
    conv_weights<<<2048, 256, 0, stream>>>(W_vv, W_vc, bW1, uW1, WcT, WgT);
    hist_kernel<<<(NA + 255) / 256, 256, 0, stream>>>(mol_id, bins, NA);
    scan_kernel<<<1, 1024, 0, stream>>>(bins, offs, cursor, NM);
    scatter_kernel<<<(NA + 255) / 256, 256, 0, stream>>>(mol_id, cursor, sorted, NA);
    fused_kernel<<<(NA + 127) / 128, 512, 0, stream>>>(
        ha_prev, c_atom, WcT, WgT, haB, G, outU, ub1, uW2, ub2, NA, hasG ? 1 : 0);
    hm_kernel<<<NM, 256, 0, stream>>>(haB, sorted, offs, hm, NM);

    if (hasG) {
        bond_stream<<<2048, 256, 0, stream>>>(G, bidx, bb1, bW2, bb2, outB, NB, 2048 * 4);
    } else {
        bond_gemm<<<(NB + 63) / 64, 512, 0, stream>>>(haB, bidx, WgT, bb1, bW2, bb2, outB, NB);
        uni_kernel<<<(NA + 63) / 64, 512, 0, stream>>>(haB, WgT, ub1, uW2, ub2, outU, NA);
    }
    done_kernel<<<(NM + 3) / 4, 256, 0, stream>>>(hm, dW1, db1, dW2, db2, outD, NM);
}

// Round 9
// 1046.976 us; speedup vs baseline: 1.0958x; 1.0958x over previous
//
#include <hip/hip_runtime.h>
#include <hip/hip_bf16.h>
#include <math.h>

typedef __attribute__((ext_vector_type(8))) short bf16x8;
typedef __attribute__((ext_vector_type(4))) float f32x4;

static __device__ __forceinline__ unsigned short f2bf(float f) {
    union { float f; unsigned u; } v; v.f = f;
    unsigned r = v.u + 0x7fffu + ((v.u >> 16) & 1u);
    return (unsigned short)(r >> 16);
}

#define GLOAD16(g, l) __builtin_amdgcn_global_load_lds( \
    (const __attribute__((address_space(1))) void*)(g), \
    (__attribute__((address_space(3))) void*)(l), 16, 0, 0)

// ---------------- fp8 e4m3 (OCP) helpers: HW cvt if available ---------------
#if defined(__has_builtin)
#  if __has_builtin(__builtin_amdgcn_cvt_pk_fp8_f32) && __has_builtin(__builtin_amdgcn_cvt_pk_f32_fp8)
#    define HAVE_FP8_CVT 1
#  endif
#endif
#ifndef HAVE_FP8_CVT
#  define HAVE_FP8_CVT 0
#endif

static __device__ __forceinline__ float f8dec_sw(unsigned b) {
    unsigned s = b >> 7, e = (b >> 3) & 15, m = b & 7;
    float v = e ? ldexpf((float)(8 + m), (int)e - 10) : ldexpf((float)m, -9);
    return s ? -v : v;
}
static __device__ __forceinline__ unsigned char f8enc_sw(float x) {
    union { float f; unsigned u; } v; v.f = x;
    unsigned s = (v.u >> 31) << 7;
    float ax = fabsf(x);
    if (ax >= 448.f) return (unsigned char)(s | 0x7E);
    if (ax < 0.015625f) { int m = (int)(ax * 512.f + 0.5f); return (unsigned char)(s | m); }
    int e; float fr = frexpf(ax, &e);
    int q = (int)(fr * 16.f + 0.5f);
    if (q == 16) { q = 8; e += 1; }
    if (e - 1 > 8) return (unsigned char)(s | 0x7E);
    return (unsigned char)(s | ((e - 1 + 7) << 3) | (q - 8));
}
static __device__ __forceinline__ unsigned char f8e(float v) {
#if HAVE_FP8_CVT
    return (unsigned char)(__builtin_amdgcn_cvt_pk_fp8_f32(v, v, 0, false) & 0xFF);
#else
    return f8enc_sw(v);
#endif
}
static __device__ __forceinline__ void f8d2_lo(unsigned w, float& x, float& y) {
#if HAVE_FP8_CVT
    auto r = __builtin_amdgcn_cvt_pk_f32_fp8((int)w, false);
    x = r[0]; y = r[1];
#else
    x = f8dec_sw(w & 0xFF); y = f8dec_sw((w >> 8) & 0xFF);
#endif
}
static __device__ __forceinline__ void f8d2_hi(unsigned w, float& x, float& y) {
#if HAVE_FP8_CVT
    auto r = __builtin_amdgcn_cvt_pk_f32_fp8((int)w, true);
    x = r[0]; y = r[1];
#else
    x = f8dec_sw((w >> 16) & 0xFF); y = f8dec_sw((w >> 24) & 0xFF);
#endif
}

// ---------------------------------------------------------------------------
// Weight conversion.
// WcT: plane-major dst[((k>>3)*256 + n)*8 + (k&7)], K=512 (vv|vc), N=256.
// WgT: K=256, N=1536 = [W1a(512) | W1b(512) | uW1(512)]
// ---------------------------------------------------------------------------
__global__ __launch_bounds__(256) void conv_weights(
    const float* __restrict__ Wvv, const float* __restrict__ Wvc,
    const float* __restrict__ bW1, const float* __restrict__ uW1,
    unsigned short* __restrict__ WcT, unsigned short* __restrict__ WgT)
{
    int idx = blockIdx.x * 256 + threadIdx.x;
    if (idx < 131072) {                       // WcT
        int n = idx & 255, k = idx >> 8;
        float s = (k < 256) ? Wvv[k * 256 + n] : Wvc[(k - 256) * 256 + n];
        WcT[((k >> 3) * 256 + n) * 8 + (k & 7)] = f2bf(s);
    } else {                                  // WgT: 393216 elems
        int t = idx - 131072;
        int k = t / 1536, n2 = t - k * 1536;
        float s;
        if (n2 < 512)       s = bW1[k * 512 + n2];
        else if (n2 < 1024) s = bW1[(256 + k) * 512 + (n2 - 512)];
        else                s = uW1[k * 512 + (n2 - 1024)];
        WgT[((k >> 3) * 1536 + n2) * 8 + (k & 7)] = f2bf(s);
    }
}

// ---------------------------------------------------------------------------
// FUSED: phase1 ha = relu(ha_prev@Wvv + c_atom@Wvc), ha[0]=0 ->
//          haB store + hm fp32 atomics (drain overlaps phase 2) + LDS tile
//        phase2 [Ga|Gb] fp8 + uni logits, K=256 from LDS, B from L2.
// Phase 2 is ONE live GEMM body (#pragma unroll 1, no B-prefetch) to stay
// under the 128-reg cap (r8 spilled 1.3 GB of scratch with 6 inlined bodies).
// ---------------------------------------------------------------------------
__global__ __launch_bounds__(512, 4) void fused_kernel(
    const float* __restrict__ ha_prev, const float* __restrict__ c_atom,
    const unsigned short* __restrict__ WcT, const unsigned short* __restrict__ WgT,
    const int* __restrict__ mol_id, unsigned short* __restrict__ haB,
    float* __restrict__ hm, unsigned char* __restrict__ G,
    float* __restrict__ outU, const float* __restrict__ ub1,
    const float* __restrict__ uW2, const float* __restrict__ ub2,
    int NA, int doG)
{
    __shared__ __align__(16) unsigned short As[4][128][64];   // 64 KB
    __shared__ float obuf[128];

    const int tid = threadIdx.x;
    const int wv = tid >> 6, lane = tid & 63;
    const int wr = wv >> 2, wc = wv & 3;
    const int c15 = lane & 15, kq = lane >> 4;
    const int xm3 = (c15 & 7) << 3;
    const int m0 = blockIdx.x * 128;

    // ---------------- phase 1: ha GEMM (K=512, N=256) ----------------
    const int cr0 = tid >> 3, chc = tid & 7;
    const int cr1 = (512 + tid) >> 3;
    int row0 = m0 + cr0; if (row0 >= NA) row0 = NA - 1;
    int row1 = m0 + cr1; if (row1 >= NA) row1 = NA - 1;

    f32x4 v00, v01, v10, v11;
    #define HA_LOAD(ks) { \
        const float* src = ((ks) < 4) ? ha_prev : c_atom; \
        const int kb = ((ks) & 3) * 64 + chc * 8; \
        const float* s0 = src + (size_t)row0 * 256 + kb; \
        const float* s1 = src + (size_t)row1 * 256 + kb; \
        v00 = *(const f32x4*)s0; v01 = *(const f32x4*)(s0 + 4); \
        v10 = *(const f32x4*)s1; v11 = *(const f32x4*)(s1 + 4); }
    #define HA_WRITE(buf) { \
        bf16x8 p0, p1; \
        p0[0]=(short)f2bf(v00[0]); p0[1]=(short)f2bf(v00[1]); p0[2]=(short)f2bf(v00[2]); p0[3]=(short)f2bf(v00[3]); \
        p0[4]=(short)f2bf(v01[0]); p0[5]=(short)f2bf(v01[1]); p0[6]=(short)f2bf(v01[2]); p0[7]=(short)f2bf(v01[3]); \
        p1[0]=(short)f2bf(v10[0]); p1[1]=(short)f2bf(v10[1]); p1[2]=(short)f2bf(v10[2]); p1[3]=(short)f2bf(v10[3]); \
        p1[4]=(short)f2bf(v11[0]); p1[5]=(short)f2bf(v11[1]); p1[6]=(short)f2bf(v11[2]); p1[7]=(short)f2bf(v11[3]); \
        *(bf16x8*)&As[buf][cr0][(chc * 8) ^ ((cr0 & 7) << 3)] = p0; \
        *(bf16x8*)&As[buf][cr1][(chc * 8) ^ ((cr1 & 7) << 3)] = p1; }

    f32x4 acc[4][4];
#pragma unroll
    for (int m = 0; m < 4; ++m)
#pragma unroll
        for (int n = 0; n < 4; ++n) acc[m][n] = (f32x4){0.f, 0.f, 0.f, 0.f};

    HA_LOAD(0); HA_WRITE(0);
    __syncthreads();

    for (int ks = 0; ks < 8; ++ks) {
        if (ks < 7) HA_LOAD(ks + 1);
        const int buf = ks & 1;
#pragma unroll
        for (int kk = 0; kk < 2; ++kk) {
            bf16x8 aF[4], bF[4];
            const int plane = ks * 8 + kk * 4 + kq;
#pragma unroll
            for (int n = 0; n < 4; ++n)
                bF[n] = *(const bf16x8*)(WcT + ((size_t)plane * 256 + wc * 64 + n * 16 + c15) * 8);
#pragma unroll
            for (int m = 0; m < 4; ++m)
                aF[m] = *(const bf16x8*)&As[buf][wr * 64 + m * 16 + c15][(kk * 32 + kq * 8) ^ xm3];
#pragma unroll
            for (int m = 0; m < 4; ++m)
#pragma unroll
                for (int n = 0; n < 4; ++n)
                    acc[m][n] = __builtin_amdgcn_mfma_f32_16x16x32_bf16(aF[m], bF[n], acc[m][n], 0, 0, 0);
        }
        if (ks < 7) HA_WRITE((ks + 1) & 1);
        __syncthreads();
    }

    // phase-1 epilogue: relu, zero row0, haB store, hm atomics, LDS deposit
    if (tid < 128) obuf[tid] = 0.f;
#pragma unroll
    for (int m = 0; m < 4; ++m) {
#pragma unroll
        for (int reg = 0; reg < 4; ++reg) {
            int rl = wr * 64 + m * 16 + kq * 4 + reg;
            int row = m0 + rl;
            bool z = (row == 0);
            bool ok = (row < NA);
            int mol = (ok && !z) ? mol_id[row] : 0;
#pragma unroll
            for (int n = 0; n < 4; ++n) {
                int col = wc * 64 + n * 16 + c15;
                float v = fmaxf(acc[m][n][reg], 0.f);
                if (z) v = 0.f;
                unsigned short bv = f2bf(v);
                if (ok) {
                    haB[(size_t)row * 256 + col] = bv;
                    if (!z) atomicAdd(&hm[mol * 256 + col], v);
                }
                As[wc][rl][(((col >> 3) & 7) ^ (rl & 7)) * 8 + (col & 7)] = bv;
            }
        }
    }
    if (!doG) return;
    __syncthreads();

    // -------- phase 2: [Ga|Gb|uni] (K=256 from LDS), 6 col-tiles ----------
    const int rg = wv >> 2, cg = wv & 3;
#pragma unroll 1
    for (int t6 = 0; t6 < 6; ++t6) {
        const int nbc = t6 >> 1;
        const int colbase = nbc * 512 + cg * 128 + (t6 & 1) * 64;
        f32x4 a2[4][4];
#pragma unroll
        for (int m = 0; m < 4; ++m)
#pragma unroll
            for (int n = 0; n < 4; ++n) a2[m][n] = (f32x4){0.f, 0.f, 0.f, 0.f};

#pragma unroll
        for (int s = 0; s < 8; ++s) {
            bf16x8 br[4], aF[4];
            const int pl = s * 4 + kq;
#pragma unroll
            for (int n = 0; n < 4; ++n)
                br[n] = *(const bf16x8*)(WgT + ((size_t)pl * 1536 + colbase + n * 16 + c15) * 8);
#pragma unroll
            for (int m = 0; m < 4; ++m) {
                int r = rg * 64 + m * 16 + c15;
                aF[m] = *(const bf16x8*)&As[s >> 1][r][(((s & 1) * 4 + kq) ^ (r & 7)) * 8];
            }
#pragma unroll
            for (int m = 0; m < 4; ++m)
#pragma unroll
                for (int n = 0; n < 4; ++n)
                    a2[m][n] = __builtin_amdgcn_mfma_f32_16x16x32_bf16(aF[m], br[n], a2[m][n], 0, 0, 0);
        }

        if (nbc < 2) {
#pragma unroll
            for (int m = 0; m < 4; ++m) {
#pragma unroll
                for (int reg = 0; reg < 4; ++reg) {
                    int row = m0 + rg * 64 + m * 16 + kq * 4 + reg;
                    if (row >= NA) continue;
#pragma unroll
                    for (int n = 0; n < 4; ++n) {
                        int col = colbase + n * 16 + c15;
                        G[(size_t)row * 1024 + col] = f8e(a2[m][n][reg]);
                    }
                }
            }
        } else {
            float b1c[4], w2c[4];
#pragma unroll
            for (int n = 0; n < 4; ++n) {
                int col = colbase - 1024 + n * 16 + c15;
                b1c[n] = ub1[col];
                w2c[n] = uW2[col];
            }
#pragma unroll
            for (int m = 0; m < 4; ++m) {
#pragma unroll
                for (int reg = 0; reg < 4; ++reg) {
                    float s0 = 0.f;
#pragma unroll
                    for (int n = 0; n < 4; ++n)
                        s0 += fmaxf(a2[m][n][reg] + b1c[n], 0.f) * w2c[n];
#pragma unroll
                    for (int off = 1; off < 16; off <<= 1) s0 += __shfl_xor(s0, off);
                    if (c15 == 0)
                        atomicAdd(&obuf[rg * 64 + m * 16 + kq * 4 + reg], s0);
                }
            }
        }
    }
    __syncthreads();
    if (tid < 128) {
        int row = m0 + tid;
        if (row < NA) outU[row] = obuf[tid] + ub2[0];
    }
}

// ---------------------------------------------------------------------------
// bond_stream: out[e] = relu(Ga[b0] + Gb[b1] + b1) @ W2 + b2.
// ---------------------------------------------------------------------------
__global__ __launch_bounds__(256) void bond_stream(
    const unsigned char* __restrict__ G, const int* __restrict__ bidx,
    const float* __restrict__ b1, const float* __restrict__ W2,
    const float* __restrict__ b2, float* __restrict__ outB, int NB, int nwaves)
{
    const int lane = threadIdx.x & 63;
    const int wid = (blockIdx.x * blockDim.x + threadIdx.x) >> 6;

    float b1c[8], w2c[8][5];
#pragma unroll
    for (int i = 0; i < 8; ++i) {
        int h = lane * 8 + i;
        b1c[i] = b1[h];
#pragma unroll
        for (int j = 0; j < 5; ++j) w2c[i][j] = W2[h * 5 + j];
    }
    float bb[5];
#pragma unroll
    for (int j = 0; j < 5; ++j) bb[j] = b2[j];

    int e = wid;
    if (e >= NB) return;
    int2 ep = ((const int2*)bidx)[e];
    int2 epN = (e + nwaves < NB) ? ((const int2*)bidx)[e + nwaves] : ep;
    uint2 ga = *(const uint2*)(G + (size_t)ep.x * 1024 + lane * 8);
    uint2 gb = *(const uint2*)(G + (size_t)ep.y * 1024 + 512 + lane * 8);

    while (e < NB) {
        int en = e + nwaves;
        uint2 gaN, gbN; int2 epN2 = epN;
        if (en < NB) {
            gaN = *(const uint2*)(G + (size_t)epN.x * 1024 + lane * 8);
            gbN = *(const uint2*)(G + (size_t)epN.y * 1024 + 512 + lane * 8);
            int e2 = en + nwaves;
            if (e2 < NB) epN2 = ((const int2*)bidx)[e2];
        }
        float s[5] = {0.f, 0.f, 0.f, 0.f, 0.f};
#pragma unroll
        for (int half = 0; half < 2; ++half) {
            unsigned wa = half ? ga.y : ga.x;
            unsigned wb = half ? gb.y : gb.x;
            float a0v, a1v, a2v, a3v, b0v, b1v, b2v, b3v;
            f8d2_lo(wa, a0v, a1v); f8d2_hi(wa, a2v, a3v);
            f8d2_lo(wb, b0v, b1v); f8d2_hi(wb, b2v, b3v);
            float hv[4] = { a0v + b0v, a1v + b1v, a2v + b2v, a3v + b3v };
#pragma unroll
            for (int t = 0; t < 4; ++t) {
                int i = half * 4 + t;
                float p = fmaxf(hv[t] + b1c[i], 0.f);
#pragma unroll
                for (int j = 0; j < 5; ++j) s[j] += p * w2c[i][j];
            }
        }
#pragma unroll
        for (int off = 1; off < 64; off <<= 1)
#pragma unroll
            for (int j = 0; j < 5; ++j) s[j] += __shfl_xor(s[j], off);
        if (lane == 0) {
#pragma unroll
            for (int j = 0; j < 5; ++j) outB[(size_t)e * 5 + j] = s[j] + bb[j];
        }
        e = en; ga = gaN; gb = gbN; epN = epN2;
    }
}

// ---------------------------------------------------------------------------
// FALLBACK (small ws): fused bond GEMM on WgT layout.
// ---------------------------------------------------------------------------
__global__ __launch_bounds__(512, 4) void bond_gemm(
    const unsigned short* __restrict__ haB, const int* __restrict__ bidx,
    const unsigned short* __restrict__ WgT, const float* __restrict__ b1,
    const float* __restrict__ W2, const float* __restrict__ b2,
    float* __restrict__ outB, int NB)
{
    __shared__ __align__(16) unsigned short As[8 * 64 * 64];
    __shared__ float obuf[64][5];

    const int tid = threadIdx.x;
    const int wv = tid >> 6, lane = tid & 63;
    const int c15 = lane & 15, kq = lane >> 4;
    const int b0 = blockIdx.x * 64;

    if (tid < 320) ((float*)obuf)[tid] = 0.f;

    {
        const int ep = wv >> 2, koff = (wv & 3) * 64;
        const int rsub = lane >> 3, csub = lane & 7;
        int eidxs[8];
#pragma unroll
        for (int j = 0; j < 8; ++j) {
            int gbd = b0 + j * 8 + rsub; if (gbd >= NB) gbd = 0;
            eidxs[j] = bidx[gbd * 2 + ep];
        }
#pragma unroll
        for (int j = 0; j < 8; ++j) {
            int r = j * 8 + rsub;
            GLOAD16(haB + (size_t)eidxs[j] * 256 + koff + (size_t)((csub ^ (r & 7)) * 8),
                    As + wv * 4096 + j * 512);
        }
    }
    __syncthreads();

    f32x4 acc[4][4];
#pragma unroll
    for (int m = 0; m < 4; ++m)
#pragma unroll
        for (int n = 0; n < 4; ++n) acc[m][n] = (f32x4){0.f, 0.f, 0.f, 0.f};

#pragma unroll 1
    for (int s = 0; s < 16; ++s) {
        const int pl = s * 4 + kq;
        bf16x8 br[4], aF[4];
#pragma unroll
        for (int n = 0; n < 4; ++n)
            br[n] = *(const bf16x8*)(WgT + ((size_t)(pl & 31) * 1536 + (pl >> 5) * 512 + wv * 64 + n * 16 + c15) * 8);
        const int ks = s >> 1, kk = s & 1;
#pragma unroll
        for (int m = 0; m < 4; ++m) {
            int r = m * 16 + c15;
            aF[m] = *(const bf16x8*)&As[ks * 4096 + r * 64 + (((kk * 4 + kq) ^ (r & 7)) * 8)];
        }
#pragma unroll
        for (int m = 0; m < 4; ++m)
#pragma unroll
            for (int n = 0; n < 4; ++n)
                acc[m][n] = __builtin_amdgcn_mfma_f32_16x16x32_bf16(aF[m], br[n], acc[m][n], 0, 0, 0);
    }

    float b1c[4], w2c[4][5];
#pragma unroll
    for (int n = 0; n < 4; ++n) {
        int col = wv * 64 + n * 16 + c15;
        b1c[n] = b1[col];
#pragma unroll
        for (int j = 0; j < 5; ++j) w2c[n][j] = W2[col * 5 + j];
    }
#pragma unroll
    for (int m = 0; m < 4; ++m) {
#pragma unroll
        for (int reg = 0; reg < 4; ++reg) {
            float s[5] = {0.f, 0.f, 0.f, 0.f, 0.f};
#pragma unroll
            for (int n = 0; n < 4; ++n) {
                float p = fmaxf(acc[m][n][reg] + b1c[n], 0.f);
#pragma unroll
                for (int j = 0; j < 5; ++j) s[j] += p * w2c[n][j];
            }
#pragma unroll
            for (int off = 1; off < 16; off <<= 1)
#pragma unroll
                for (int j = 0; j < 5; ++j) s[j] += __shfl_xor(s[j], off);
            if (c15 == 0) {
                int rl = m * 16 + kq * 4 + reg;
#pragma unroll
                for (int j = 0; j < 5; ++j) atomicAdd(&obuf[rl][j], s[j]);
            }
        }
    }
    __syncthreads();
    {
        int r = tid >> 3, j = tid & 7;
        if (j < 5) {
            int row = b0 + r;
            if (row < NB) outB[(size_t)row * 5 + j] = obuf[r][j] + b2[j];
        }
    }
}

// ---------------------------------------------------------------------------
// FALLBACK uni GEMM, B = WgT cols 1024..1535 (stride 1536).
// ---------------------------------------------------------------------------
__global__ __launch_bounds__(512, 4) void uni_kernel(
    const unsigned short* __restrict__ haB, const unsigned short* __restrict__ WgT,
    const float* __restrict__ b1, const float* __restrict__ W2,
    const float* __restrict__ b2, float* __restrict__ outU, int NA)
{
    __shared__ __align__(16) unsigned short As[4 * 64 * 64];
    __shared__ float obuf[64];

    const int tid = threadIdx.x;
    const int wv = tid >> 6, lane = tid & 63;
    const int c15 = lane & 15, kq = lane >> 4;
    const int a0 = blockIdx.x * 64;

    if (tid < 64) obuf[tid] = 0.f;

    {
        const int kt = wv >> 1, koff = kt * 64;
        const int rsub = lane >> 3, csub = lane & 7;
#pragma unroll
        for (int jj = 0; jj < 4; ++jj) {
            int j = (wv & 1) * 4 + jj;
            int r = j * 8 + rsub;
            int ga = a0 + r; if (ga >= NA) ga = NA - 1;
            GLOAD16(haB + (size_t)ga * 256 + koff + (size_t)((csub ^ (r & 7)) * 8),
                    As + kt * 4096 + j * 512);
        }
    }
    __syncthreads();

    f32x4 acc[4][4];
#pragma unroll
    for (int m = 0; m < 4; ++m)
#pragma unroll
        for (int n = 0; n < 4; ++n) acc[m][n] = (f32x4){0.f, 0.f, 0.f, 0.f};

#pragma unroll 1
    for (int s = 0; s < 8; ++s) {
        const int pl = s * 4 + kq;
        bf16x8 br[4], aF[4];
#pragma unroll
        for (int n = 0; n < 4; ++n)
            br[n] = *(const bf16x8*)(WgT + ((size_t)pl * 1536 + 1024 + wv * 64 + n * 16 + c15) * 8);
        const int ks = s >> 1, kk = s & 1;
#pragma unroll
        for (int m = 0; m < 4; ++m) {
            int r = m * 16 + c15;
            aF[m] = *(const bf16x8*)&As[ks * 4096 + r * 64 + (((kk * 4 + kq) ^ (r & 7)) * 8)];
        }
#pragma unroll
        for (int m = 0; m < 4; ++m)
#pragma unroll
            for (int n = 0; n < 4; ++n)
                acc[m][n] = __builtin_amdgcn_mfma_f32_16x16x32_bf16(aF[m], br[n], acc[m][n], 0, 0, 0);
    }

    float b1c[4], w2c[4];
#pragma unroll
    for (int n = 0; n < 4; ++n) {
        int col = wv * 64 + n * 16 + c15;
        b1c[n] = b1[col];
        w2c[n] = W2[col];
    }
#pragma unroll
    for (int m = 0; m < 4; ++m) {
#pragma unroll
        for (int reg = 0; reg < 4; ++reg) {
            float s = 0.f;
#pragma unroll
            for (int n = 0; n < 4; ++n)
                s += fmaxf(acc[m][n][reg] + b1c[n], 0.f) * w2c[n];
#pragma unroll
            for (int off = 1; off < 16; off <<= 1) s += __shfl_xor(s, off);
            if (c15 == 0) atomicAdd(&obuf[m * 16 + kq * 4 + reg], s);
        }
    }
    __syncthreads();
    if (tid < 64) {
        int row = a0 + tid;
        if (row < NA) outU[row] = obuf[tid] + b2[0];
    }
}

// ---------------------------------------------------------------------------
// done_logits: 4 molecules per block, fp32
// ---------------------------------------------------------------------------
__global__ __launch_bounds__(256) void done_kernel(
    const float* __restrict__ hm, const float* __restrict__ W1,
    const float* __restrict__ b1, const float* __restrict__ W2,
    const float* __restrict__ b2, float* __restrict__ outD, int NM)
{
    __shared__ float rsh[4][256];
    __shared__ float red[4][4];
    const int tid = threadIdx.x;
    const int wv = tid >> 6, lane = tid & 63;
    const int mol0 = blockIdx.x * 4;
#pragma unroll
    for (int q = 0; q < 4; ++q)
        rsh[q][tid] = (mol0 + q < NM) ? hm[(size_t)(mol0 + q) * 256 + tid] : 0.f;
    __syncthreads();
    float h[4][2];
#pragma unroll
    for (int q = 0; q < 4; ++q) { h[q][0] = 0.f; h[q][1] = 0.f; }
    for (int k = 0; k < 256; ++k) {
        float w0 = W1[k * 512 + tid];
        float w1 = W1[k * 512 + tid + 256];
#pragma unroll
        for (int q = 0; q < 4; ++q) {
            h[q][0] += rsh[q][k] * w0;
            h[q][1] += rsh[q][k] * w1;
        }
    }
    float bb0 = b1[tid], bb1v = b1[tid + 256];
    float ww0 = W2[tid], ww1 = W2[tid + 256];
#pragma unroll
    for (int q = 0; q < 4; ++q) {
        float p = fmaxf(h[q][0] + bb0, 0.f) * ww0 + fmaxf(h[q][1] + bb1v, 0.f) * ww1;
#pragma unroll
        for (int off = 1; off < 64; off <<= 1) p += __shfl_xor(p, off);
        if (lane == 0) red[q][wv] = p;
    }
    __syncthreads();
    if (tid < 4 && mol0 + tid < NM)
        outD[mol0 + tid] = red[tid][0] + red[tid][1] + red[tid][2] + red[tid][3] + b2[0];
}

// ---------------------------------------------------------------------------
extern "C" void kernel_launch(void* const* d_in, const int* in_sizes, int n_in,
                              void* d_out, int out_size, void* d_ws, size_t ws_size,
                              hipStream_t stream)
{
    const float* c_atom  = (const float*)d_in[0];
    const float* ha_prev = (const float*)d_in[1];
    const float* W_vv    = (const float*)d_in[2];
    const float* W_vc    = (const float*)d_in[3];
    const float* bW1     = (const float*)d_in[4];
    const float* bb1     = (const float*)d_in[5];
    const float* bW2     = (const float*)d_in[6];
    const float* bb2     = (const float*)d_in[7];
    const float* uW1     = (const float*)d_in[8];
    const float* ub1     = (const float*)d_in[9];
    const float* uW2     = (const float*)d_in[10];
    const float* ub2     = (const float*)d_in[11];
    const float* dW1     = (const float*)d_in[12];
    const float* db1     = (const float*)d_in[13];
    const float* dW2     = (const float*)d_in[14];
    const float* db2     = (const float*)d_in[15];
    const int* mol_id    = (const int*)d_in[16];
    const int* bidx      = (const int*)d_in[17];

    const int H = 256, BS = 5;
    const int NA = in_sizes[0] / H;
    const int NB = in_sizes[17] / 2;
    const int NM = out_size - NB * BS - NA;

    float* out  = (float*)d_out;
    float* outB = out;
    float* outU = out + (size_t)NB * BS;
    float* outD = outU + NA;

    char* ws = (char*)d_ws;
    size_t off = 0;
    unsigned short* haB = (unsigned short*)(ws + off);
    off += (size_t)NA * H * 2;            off = (off + 255) & ~(size_t)255;
    float* hm = (float*)(ws + off);
    off += (size_t)NM * H * 4;            off = (off + 255) & ~(size_t)255;
    unsigned short* WcT = (unsigned short*)(ws + off);
    off += (size_t)131072 * 2;            off = (off + 255) & ~(size_t)255;
    unsigned short* WgT = (unsigned short*)(ws + off);
    off += (size_t)393216 * 2;            off = (off + 255) & ~(size_t)255;
    unsigned char* G = (unsigned char*)(ws + off);
    size_t need_G = off + (size_t)NA * 1024;

    const bool hasG = ws_size >= need_G;

    hipMemsetAsync(hm, 0, (size_t)NM * H * 4, stream);
    conv_weights<<<2048, 256, 0, stream>>>(W_vv, W_vc, bW1, uW1, WcT, WgT);
    fused_kernel<<<(NA + 127) / 128, 512, 0, stream>>>(
        ha_prev, c_atom, WcT, WgT, mol_id, haB, hm, G,
        outU, ub1, uW2, ub2, NA, hasG ? 1 : 0);

    if (hasG) {
        bond_stream<<<2048, 256, 0, stream>>>(G, bidx, bb1, bW2, bb2, outB, NB, 2048 * 4);
    } else {
        bond_gemm<<<(NB + 63) / 64, 512, 0, stream>>>(haB, bidx, WgT, bb1, bW2, bb2, outB, NB);
        uni_kernel<<<(NA + 63) / 64, 512, 0, stream>>>(haB, WgT, ub1, uW2, ub2, outU, NA);
    }
    done_kernel<<<(NM + 3) / 4, 256, 0, stream>>>(hm, dW1, db1, dW2, db2, outD, NM);
}

// Round 10
// 651.248 us; speedup vs baseline: 1.7616x; 1.6076x over previous
//
#include <hip/hip_runtime.h>
#include <hip/hip_bf16.h>
#include <math.h>

typedef __attribute__((ext_vector_type(8))) short bf16x8;
typedef __attribute__((ext_vector_type(4))) float f32x4;

static __device__ __forceinline__ unsigned short f2bf(float f) {
    union { float f; unsigned u; } v; v.f = f;
    unsigned r = v.u + 0x7fffu + ((v.u >> 16) & 1u);
    return (unsigned short)(r >> 16);
}
static __device__ __forceinline__ float bf2f(unsigned short b) {
    union { unsigned u; float f; } v; v.u = ((unsigned)b) << 16;
    return v.f;
}

#define GLOAD16(g, l) __builtin_amdgcn_global_load_lds( \
    (const __attribute__((address_space(1))) void*)(g), \
    (__attribute__((address_space(3))) void*)(l), 16, 0, 0)

// ---------------- fp8 e4m3 (OCP) helpers: HW cvt if available ---------------
#if defined(__has_builtin)
#  if __has_builtin(__builtin_amdgcn_cvt_pk_fp8_f32) && __has_builtin(__builtin_amdgcn_cvt_pk_f32_fp8)
#    define HAVE_FP8_CVT 1
#  endif
#endif
#ifndef HAVE_FP8_CVT
#  define HAVE_FP8_CVT 0
#endif

static __device__ __forceinline__ float f8dec_sw(unsigned b) {
    unsigned s = b >> 7, e = (b >> 3) & 15, m = b & 7;
    float v = e ? ldexpf((float)(8 + m), (int)e - 10) : ldexpf((float)m, -9);
    return s ? -v : v;
}
static __device__ __forceinline__ unsigned char f8enc_sw(float x) {
    union { float f; unsigned u; } v; v.f = x;
    unsigned s = (v.u >> 31) << 7;
    float ax = fabsf(x);
    if (ax >= 448.f) return (unsigned char)(s | 0x7E);
    if (ax < 0.015625f) { int m = (int)(ax * 512.f + 0.5f); return (unsigned char)(s | m); }
    int e; float fr = frexpf(ax, &e);
    int q = (int)(fr * 16.f + 0.5f);
    if (q == 16) { q = 8; e += 1; }
    if (e - 1 > 8) return (unsigned char)(s | 0x7E);
    return (unsigned char)(s | ((e - 1 + 7) << 3) | (q - 8));
}
static __device__ __forceinline__ unsigned char f8e(float v) {
#if HAVE_FP8_CVT
    return (unsigned char)(__builtin_amdgcn_cvt_pk_fp8_f32(v, v, 0, false) & 0xFF);
#else
    return f8enc_sw(v);
#endif
}
static __device__ __forceinline__ void f8d2_lo(unsigned w, float& x, float& y) {
#if HAVE_FP8_CVT
    auto r = __builtin_amdgcn_cvt_pk_f32_fp8((int)w, false);
    x = r[0]; y = r[1];
#else
    x = f8dec_sw(w & 0xFF); y = f8dec_sw((w >> 8) & 0xFF);
#endif
}
static __device__ __forceinline__ void f8d2_hi(unsigned w, float& x, float& y) {
#if HAVE_FP8_CVT
    auto r = __builtin_amdgcn_cvt_pk_f32_fp8((int)w, true);
    x = r[0]; y = r[1];
#else
    x = f8dec_sw((w >> 16) & 0xFF); y = f8dec_sw((w >> 24) & 0xFF);
#endif
}

// ---------------------------------------------------------------------------
// Weight conversion.
// WcT: plane-major dst[((k>>3)*256 + n)*8 + (k&7)], K=512 (vv|vc), N=256.
// WgT: K=256, N=1536 = [W1a(512) | W1b(512) | uW1(512)]
// ---------------------------------------------------------------------------
__global__ __launch_bounds__(256) void conv_weights(
    const float* __restrict__ Wvv, const float* __restrict__ Wvc,
    const float* __restrict__ bW1, const float* __restrict__ uW1,
    unsigned short* __restrict__ WcT, unsigned short* __restrict__ WgT)
{
    int idx = blockIdx.x * 256 + threadIdx.x;
    if (idx < 131072) {                       // WcT
        int n = idx & 255, k = idx >> 8;
        float s = (k < 256) ? Wvv[k * 256 + n] : Wvc[(k - 256) * 256 + n];
        WcT[((k >> 3) * 256 + n) * 8 + (k & 7)] = f2bf(s);
    } else {                                  // WgT: 393216 elems
        int t = idx - 131072;
        int k = t / 1536, n2 = t - k * 1536;
        float s;
        if (n2 < 512)       s = bW1[k * 512 + n2];
        else if (n2 < 1024) s = bW1[(256 + k) * 512 + (n2 - 512)];
        else                s = uW1[k * 512 + (n2 - 1024)];
        WgT[((k >> 3) * 1536 + n2) * 8 + (k & 7)] = f2bf(s);
    }
}

// ---------------------------------------------------------------------------
// ha = relu(ha_prev @ W_vv + c_atom @ W_vc); ha[0]=0. Clean GEMM, no atomics.
// (r7 structure, measured <239us, no anomalies)
// ---------------------------------------------------------------------------
__global__ __launch_bounds__(512, 4) void ha_kernel(
    const float* __restrict__ ha_prev, const float* __restrict__ c_atom,
    const unsigned short* __restrict__ WcT,
    unsigned short* __restrict__ haB, int NA)
{
    __shared__ __align__(16) unsigned short As[2][128 * 64];

    const int tid = threadIdx.x;
    const int wv = tid >> 6, lane = tid & 63;
    const int wr = wv >> 2, wc = wv & 3;
    const int c15 = lane & 15, kq = lane >> 4;
    const int xm3 = (c15 & 7) << 3;
    const int m0 = blockIdx.x * 128;

    const int cr0 = tid >> 3, chc = tid & 7;
    const int cr1 = (512 + tid) >> 3;
    int row0 = m0 + cr0; if (row0 >= NA) row0 = NA - 1;
    int row1 = m0 + cr1; if (row1 >= NA) row1 = NA - 1;

    f32x4 v00, v01, v10, v11;
    #define HA_LOAD(ks) { \
        const float* src = ((ks) < 4) ? ha_prev : c_atom; \
        const int kb = ((ks) & 3) * 64 + chc * 8; \
        const float* s0 = src + (size_t)row0 * 256 + kb; \
        const float* s1 = src + (size_t)row1 * 256 + kb; \
        v00 = *(const f32x4*)s0; v01 = *(const f32x4*)(s0 + 4); \
        v10 = *(const f32x4*)s1; v11 = *(const f32x4*)(s1 + 4); }
    #define HA_WRITE(buf) { \
        bf16x8 p0, p1; \
        p0[0]=(short)f2bf(v00[0]); p0[1]=(short)f2bf(v00[1]); p0[2]=(short)f2bf(v00[2]); p0[3]=(short)f2bf(v00[3]); \
        p0[4]=(short)f2bf(v01[0]); p0[5]=(short)f2bf(v01[1]); p0[6]=(short)f2bf(v01[2]); p0[7]=(short)f2bf(v01[3]); \
        p1[0]=(short)f2bf(v10[0]); p1[1]=(short)f2bf(v10[1]); p1[2]=(short)f2bf(v10[2]); p1[3]=(short)f2bf(v10[3]); \
        p1[4]=(short)f2bf(v11[0]); p1[5]=(short)f2bf(v11[1]); p1[6]=(short)f2bf(v11[2]); p1[7]=(short)f2bf(v11[3]); \
        *(bf16x8*)&As[buf][cr0 * 64 + ((chc * 8) ^ ((cr0 & 7) << 3))] = p0; \
        *(bf16x8*)&As[buf][cr1 * 64 + ((chc * 8) ^ ((cr1 & 7) << 3))] = p1; }

    f32x4 acc[4][4];
#pragma unroll
    for (int m = 0; m < 4; ++m)
#pragma unroll
        for (int n = 0; n < 4; ++n) acc[m][n] = (f32x4){0.f, 0.f, 0.f, 0.f};

    HA_LOAD(0); HA_WRITE(0);
    __syncthreads();

    for (int ks = 0; ks < 8; ++ks) {
        if (ks < 7) HA_LOAD(ks + 1);
        const int buf = ks & 1;
#pragma unroll
        for (int kk = 0; kk < 2; ++kk) {
            bf16x8 aF[4], bF[4];
            const int plane = ks * 8 + kk * 4 + kq;
#pragma unroll
            for (int n = 0; n < 4; ++n)
                bF[n] = *(const bf16x8*)(WcT + ((size_t)plane * 256 + wc * 64 + n * 16 + c15) * 8);
#pragma unroll
            for (int m = 0; m < 4; ++m)
                aF[m] = *(const bf16x8*)&As[buf][(wr * 64 + m * 16 + c15) * 64 + ((kk * 32 + kq * 8) ^ xm3)];
#pragma unroll
            for (int m = 0; m < 4; ++m)
#pragma unroll
                for (int n = 0; n < 4; ++n)
                    acc[m][n] = __builtin_amdgcn_mfma_f32_16x16x32_bf16(aF[m], bF[n], acc[m][n], 0, 0, 0);
        }
        if (ks < 7) HA_WRITE((ks + 1) & 1);
        __syncthreads();
    }

#pragma unroll
    for (int m = 0; m < 4; ++m) {
#pragma unroll
        for (int reg = 0; reg < 4; ++reg) {
            int row = m0 + wr * 64 + m * 16 + kq * 4 + reg;
            if (row >= NA) continue;
            bool z = (row == 0);
#pragma unroll
            for (int n = 0; n < 4; ++n) {
                int col = wc * 64 + n * 16 + c15;
                float v = fmaxf(acc[m][n][reg], 0.f);
                if (z) v = 0.f;
                haB[(size_t)row * 256 + col] = f2bf(v);
            }
        }
    }
}

// ---------------------------------------------------------------------------
// g_kernel (r7 skeleton + 2 edits): per (block.x, nb): stage 128x256 ha tile,
// GEMM vs WgT slice nb. nb=0/1 -> fp8 G. nb=2 -> uni logits direct to outU
// (no Hu buffer). All slices then issue fire-and-forget hm atomics for their
// ~86-column share of the staged tile (skipping relu zeros & row 0).
// ---------------------------------------------------------------------------
__global__ __launch_bounds__(1024, 4) void g_kernel(
    const unsigned short* __restrict__ haB, const unsigned short* __restrict__ WgT,
    const int* __restrict__ mol_id, float* __restrict__ hm,
    unsigned char* __restrict__ G, float* __restrict__ outU,
    const float* __restrict__ ub1, const float* __restrict__ uW2,
    const float* __restrict__ ub2, int NA)
{
    __shared__ __align__(16) unsigned short As[4][128][64];   // 64 KB
    __shared__ float obuf[128];
    __shared__ int molS[128];

    const int tid = threadIdx.x;
    const int wv = tid >> 6, lane = tid & 63;
    const int wr = wv >> 3, wc = wv & 7;
    const int c15 = lane & 15, kq = lane >> 4;
    const int a0 = blockIdx.x * 128;
    const int nb = blockIdx.y;

    if (tid < 128) {
        obuf[tid] = 0.f;
        molS[tid] = (a0 + tid < NA) ? mol_id[a0 + tid] : 0;
    }
    {
        const int kt = wv >> 2;
        const int rsub = lane >> 3, csub = lane & 7;
#pragma unroll
        for (int j = 0; j < 4; ++j) {
            int rg = (wv & 3) * 4 + j;
            int r = rg * 8 + rsub;
            int ga = a0 + r; if (ga >= NA) ga = NA - 1;
            GLOAD16(haB + (size_t)ga * 256 + kt * 64 + (size_t)((csub ^ (r & 7)) * 8),
                    &As[kt][rg * 8][0]);
        }
    }
    __syncthreads();

    f32x4 acc[4][4];
#pragma unroll
    for (int m = 0; m < 4; ++m)
#pragma unroll
        for (int n = 0; n < 4; ++n) acc[m][n] = (f32x4){0.f, 0.f, 0.f, 0.f};

    bf16x8 breg[2][4];
#pragma unroll
    for (int n = 0; n < 4; ++n)
        breg[0][n] = *(const bf16x8*)(WgT + ((size_t)kq * 1536 + nb * 512 + wc * 64 + n * 16 + c15) * 8);

#pragma unroll
    for (int s = 0; s < 8; ++s) {
        if (s < 7) {
            const int pl = (s + 1) * 4 + kq;
#pragma unroll
            for (int n = 0; n < 4; ++n)
                breg[(s + 1) & 1][n] = *(const bf16x8*)(WgT + ((size_t)pl * 1536 + nb * 512 + wc * 64 + n * 16 + c15) * 8);
        }
        const int ks = s >> 1, kk = s & 1;
        bf16x8 aF[4];
#pragma unroll
        for (int m = 0; m < 4; ++m) {
            int r = wr * 64 + m * 16 + c15;
            aF[m] = *(const bf16x8*)&As[ks][r][((kk * 4 + kq) ^ (r & 7)) * 8];
        }
#pragma unroll
        for (int m = 0; m < 4; ++m)
#pragma unroll
            for (int n = 0; n < 4; ++n)
                acc[m][n] = __builtin_amdgcn_mfma_f32_16x16x32_bf16(aF[m], breg[s & 1][n], acc[m][n], 0, 0, 0);
    }

    if (nb < 2) {
        // fp8 G writes
#pragma unroll
        for (int m = 0; m < 4; ++m) {
#pragma unroll
            for (int reg = 0; reg < 4; ++reg) {
                int row = a0 + wr * 64 + m * 16 + kq * 4 + reg;
                if (row >= NA) continue;
#pragma unroll
                for (int n = 0; n < 4; ++n) {
                    int col = wc * 64 + n * 16 + c15;
                    G[(size_t)row * 1024 + nb * 512 + col] = f8e(acc[m][n][reg]);
                }
            }
        }
    } else {
        // uni: relu(h + ub1) @ uW2, reduce over this wave's 64 cols
        float b1c[4], w2c[4];
#pragma unroll
        for (int n = 0; n < 4; ++n) {
            int col = wc * 64 + n * 16 + c15;
            b1c[n] = ub1[col];
            w2c[n] = uW2[col];
        }
#pragma unroll
        for (int m = 0; m < 4; ++m) {
#pragma unroll
            for (int reg = 0; reg < 4; ++reg) {
                float s0 = 0.f;
#pragma unroll
                for (int n = 0; n < 4; ++n)
                    s0 += fmaxf(acc[m][n][reg] + b1c[n], 0.f) * w2c[n];
#pragma unroll
                for (int off = 1; off < 16; off <<= 1) s0 += __shfl_xor(s0, off);
                if (c15 == 0)
                    atomicAdd(&obuf[wr * 64 + m * 16 + kq * 4 + reg], s0);
            }
        }
        __syncthreads();
        if (tid < 128) {
            int row = a0 + tid;
            if (row < NA) outU[row] = obuf[tid] + ub2[0];
        }
    }

    // hm atomics for this slice's column share (fire-and-forget; drains
    // under other blocks' compute). cols [nb*86, min(nb*86+86,256)).
    {
        const int c0 = nb * 86;
        const int c1 = (c0 + 86 < 256) ? c0 + 86 : 256;
        const int rgp = tid >> 7, tc = tid & 127;
        const int c = c0 + tc;
        if (c < c1) {
            const int kt2 = c >> 6, q = (c & 63) >> 3, jj = c & 7;
#pragma unroll 4
            for (int rr = rgp; rr < 128; rr += 8) {
                int row = a0 + rr;
                if (row > 0 && row < NA) {
                    float v = bf2f(As[kt2][rr][((q ^ (rr & 7)) << 3) + jj]);
                    if (v != 0.f) atomicAdd(&hm[molS[rr] * 256 + c], v);
                }
            }
        }
    }
}

// ---------------------------------------------------------------------------
// bond_stream: out[e] = relu(Ga[b0] + Gb[b1] + b1) @ W2 + b2.
// ---------------------------------------------------------------------------
__global__ __launch_bounds__(256) void bond_stream(
    const unsigned char* __restrict__ G, const int* __restrict__ bidx,
    const float* __restrict__ b1, const float* __restrict__ W2,
    const float* __restrict__ b2, float* __restrict__ outB, int NB, int nwaves)
{
    const int lane = threadIdx.x & 63;
    const int wid = (blockIdx.x * blockDim.x + threadIdx.x) >> 6;

    float b1c[8], w2c[8][5];
#pragma unroll
    for (int i = 0; i < 8; ++i) {
        int h = lane * 8 + i;
        b1c[i] = b1[h];
#pragma unroll
        for (int j = 0; j < 5; ++j) w2c[i][j] = W2[h * 5 + j];
    }
    float bb[5];
#pragma unroll
    for (int j = 0; j < 5; ++j) bb[j] = b2[j];

    int e = wid;
    if (e >= NB) return;
    int2 ep = ((const int2*)bidx)[e];
    int2 epN = (e + nwaves < NB) ? ((const int2*)bidx)[e + nwaves] : ep;
    uint2 ga = *(const uint2*)(G + (size_t)ep.x * 1024 + lane * 8);
    uint2 gb = *(const uint2*)(G + (size_t)ep.y * 1024 + 512 + lane * 8);

    while (e < NB) {
        int en = e + nwaves;
        uint2 gaN, gbN; int2 epN2 = epN;
        if (en < NB) {
            gaN = *(const uint2*)(G + (size_t)epN.x * 1024 + lane * 8);
            gbN = *(const uint2*)(G + (size_t)epN.y * 1024 + 512 + lane * 8);
            int e2 = en + nwaves;
            if (e2 < NB) epN2 = ((const int2*)bidx)[e2];
        }
        float s[5] = {0.f, 0.f, 0.f, 0.f, 0.f};
#pragma unroll
        for (int half = 0; half < 2; ++half) {
            unsigned wa = half ? ga.y : ga.x;
            unsigned wb = half ? gb.y : gb.x;
            float a0v, a1v, a2v, a3v, b0v, b1v, b2v, b3v;
            f8d2_lo(wa, a0v, a1v); f8d2_hi(wa, a2v, a3v);
            f8d2_lo(wb, b0v, b1v); f8d2_hi(wb, b2v, b3v);
            float hv[4] = { a0v + b0v, a1v + b1v, a2v + b2v, a3v + b3v };
#pragma unroll
            for (int t = 0; t < 4; ++t) {
                int i = half * 4 + t;
                float p = fmaxf(hv[t] + b1c[i], 0.f);
#pragma unroll
                for (int j = 0; j < 5; ++j) s[j] += p * w2c[i][j];
            }
        }
#pragma unroll
        for (int off = 1; off < 64; off <<= 1)
#pragma unroll
            for (int j = 0; j < 5; ++j) s[j] += __shfl_xor(s[j], off);
        if (lane == 0) {
#pragma unroll
            for (int j = 0; j < 5; ++j) outB[(size_t)e * 5 + j] = s[j] + bb[j];
        }
        e = en; ga = gaN; gb = gbN; epN = epN2;
    }
}

// ---------------------------------------------------------------------------
// hm fallback (only when ws too small for G): atomics from haB.
// ---------------------------------------------------------------------------
__global__ __launch_bounds__(256) void hm_fallback(
    const unsigned short* __restrict__ haB, const int* __restrict__ mol_id,
    float* __restrict__ hm, int NA)
{
    int idx = blockIdx.x * 256 + threadIdx.x;
    int row = idx >> 6, c4 = (idx & 63) * 4;
    if (row == 0 || row >= NA) return;
    int mol = mol_id[row];
    const unsigned short* p = haB + (size_t)row * 256 + c4;
#pragma unroll
    for (int j = 0; j < 4; ++j) {
        float v = bf2f(p[j]);
        if (v != 0.f) atomicAdd(&hm[mol * 256 + c4 + j], v);
    }
}

// ---------------------------------------------------------------------------
// FALLBACK (small ws): fused bond GEMM on WgT layout.
// ---------------------------------------------------------------------------
__global__ __launch_bounds__(512, 4) void bond_gemm(
    const unsigned short* __restrict__ haB, const int* __restrict__ bidx,
    const unsigned short* __restrict__ WgT, const float* __restrict__ b1,
    const float* __restrict__ W2, const float* __restrict__ b2,
    float* __restrict__ outB, int NB)
{
    __shared__ __align__(16) unsigned short As[8 * 64 * 64];
    __shared__ float obuf[64][5];

    const int tid = threadIdx.x;
    const int wv = tid >> 6, lane = tid & 63;
    const int c15 = lane & 15, kq = lane >> 4;
    const int b0 = blockIdx.x * 64;

    if (tid < 320) ((float*)obuf)[tid] = 0.f;

    {
        const int ep = wv >> 2, koff = (wv & 3) * 64;
        const int rsub = lane >> 3, csub = lane & 7;
        int eidxs[8];
#pragma unroll
        for (int j = 0; j < 8; ++j) {
            int gbd = b0 + j * 8 + rsub; if (gbd >= NB) gbd = 0;
            eidxs[j] = bidx[gbd * 2 + ep];
        }
#pragma unroll
        for (int j = 0; j < 8; ++j) {
            int r = j * 8 + rsub;
            GLOAD16(haB + (size_t)eidxs[j] * 256 + koff + (size_t)((csub ^ (r & 7)) * 8),
                    As + wv * 4096 + j * 512);
        }
    }
    __syncthreads();

    f32x4 acc[4][4];
#pragma unroll
    for (int m = 0; m < 4; ++m)
#pragma unroll
        for (int n = 0; n < 4; ++n) acc[m][n] = (f32x4){0.f, 0.f, 0.f, 0.f};

#pragma unroll 1
    for (int s = 0; s < 16; ++s) {
        const int pl = s * 4 + kq;
        bf16x8 br[4], aF[4];
#pragma unroll
        for (int n = 0; n < 4; ++n)
            br[n] = *(const bf16x8*)(WgT + ((size_t)(pl & 31) * 1536 + (pl >> 5) * 512 + wv * 64 + n * 16 + c15) * 8);
        const int ks = s >> 1, kk = s & 1;
#pragma unroll
        for (int m = 0; m < 4; ++m) {
            int r = m * 16 + c15;
            aF[m] = *(const bf16x8*)&As[ks * 4096 + r * 64 + (((kk * 4 + kq) ^ (r & 7)) * 8)];
        }
#pragma unroll
        for (int m = 0; m < 4; ++m)
#pragma unroll
            for (int n = 0; n < 4; ++n)
                acc[m][n] = __builtin_amdgcn_mfma_f32_16x16x32_bf16(aF[m], br[n], acc[m][n], 0, 0, 0);
    }

    float b1c[4], w2c[4][5];
#pragma unroll
    for (int n = 0; n < 4; ++n) {
        int col = wv * 64 + n * 16 + c15;
        b1c[n] = b1[col];
#pragma unroll
        for (int j = 0; j < 5; ++j) w2c[n][j] = W2[col * 5 + j];
    }
#pragma unroll
    for (int m = 0; m < 4; ++m) {
#pragma unroll
        for (int reg = 0; reg < 4; ++reg) {
            float s[5] = {0.f, 0.f, 0.f, 0.f, 0.f};
#pragma unroll
            for (int n = 0; n < 4; ++n) {
                float p = fmaxf(acc[m][n][reg] + b1c[n], 0.f);
#pragma unroll
                for (int j = 0; j < 5; ++j) s[j] += p * w2c[n][j];
            }
#pragma unroll
            for (int off = 1; off < 16; off <<= 1)
#pragma unroll
                for (int j = 0; j < 5; ++j) s[j] += __shfl_xor(s[j], off);
            if (c15 == 0) {
                int rl = m * 16 + kq * 4 + reg;
#pragma unroll
                for (int j = 0; j < 5; ++j) atomicAdd(&obuf[rl][j], s[j]);
            }
        }
    }
    __syncthreads();
    {
        int r = tid >> 3, j = tid & 7;
        if (j < 5) {
            int row = b0 + r;
            if (row < NB) outB[(size_t)row * 5 + j] = obuf[r][j] + b2[j];
        }
    }
}

// ---------------------------------------------------------------------------
// FALLBACK uni GEMM, B = WgT cols 1024..1535 (stride 1536).
// ---------------------------------------------------------------------------
__global__ __launch_bounds__(512, 4) void uni_kernel(
    const unsigned short* __restrict__ haB, const unsigned short* __restrict__ WgT,
    const float* __restrict__ b1, const float* __restrict__ W2,
    const float* __restrict__ b2, float* __restrict__ outU, int NA)
{
    __shared__ __align__(16) unsigned short As[4 * 64 * 64];
    __shared__ float obuf[64];

    const int tid = threadIdx.x;
    const int wv = tid >> 6, lane = tid & 63;
    const int c15 = lane & 15, kq = lane >> 4;
    const int a0 = blockIdx.x * 64;

    if (tid < 64) obuf[tid] = 0.f;

    {
        const int kt = wv >> 1, koff = kt * 64;
        const int rsub = lane >> 3, csub = lane & 7;
#pragma unroll
        for (int jj = 0; jj < 4; ++jj) {
            int j = (wv & 1) * 4 + jj;
            int r = j * 8 + rsub;
            int ga = a0 + r; if (ga >= NA) ga = NA - 1;
            GLOAD16(haB + (size_t)ga * 256 + koff + (size_t)((csub ^ (r & 7)) * 8),
                    As + kt * 4096 + j * 512);
        }
    }
    __syncthreads();

    f32x4 acc[4][4];
#pragma unroll
    for (int m = 0; m < 4; ++m)
#pragma unroll
        for (int n = 0; n < 4; ++n) acc[m][n] = (f32x4){0.f, 0.f, 0.f, 0.f};

#pragma unroll 1
    for (int s = 0; s < 8; ++s) {
        const int pl = s * 4 + kq;
        bf16x8 br[4], aF[4];
#pragma unroll
        for (int n = 0; n < 4; ++n)
            br[n] = *(const bf16x8*)(WgT + ((size_t)pl * 1536 + 1024 + wv * 64 + n * 16 + c15) * 8);
        const int ks = s >> 1, kk = s & 1;
#pragma unroll
        for (int m = 0; m < 4; ++m) {
            int r = m * 16 + c15;
            aF[m] = *(const bf16x8*)&As[ks * 4096 + r * 64 + (((kk * 4 + kq) ^ (r & 7)) * 8)];
        }
#pragma unroll
        for (int m = 0; m < 4; ++m)
#pragma unroll
            for (int n = 0; n < 4; ++n)
                acc[m][n] = __builtin_amdgcn_mfma_f32_16x16x32_bf16(aF[m], br[n], acc[m][n], 0, 0, 0);
    }

    float b1c[4], w2c[4];
#pragma unroll
    for (int n = 0; n < 4; ++n) {
        int col = wv * 64 + n * 16 + c15;
        b1c[n] = b1[col];
        w2c[n] = W2[col];
    }
#pragma unroll
    for (int m = 0; m < 4; ++m) {
#pragma unroll
        for (int reg = 0; reg < 4; ++reg) {
            float s = 0.f;
#pragma unroll
            for (int n = 0; n < 4; ++n)
                s += fmaxf(acc[m][n][reg] + b1c[n], 0.f) * w2c[n];
#pragma unroll
            for (int off = 1; off < 16; off <<= 1) s += __shfl_xor(s, off);
            if (c15 == 0) atomicAdd(&obuf[m * 16 + kq * 4 + reg], s);
        }
    }
    __syncthreads();
    if (tid < 64) {
        int row = a0 + tid;
        if (row < NA) outU[row] = obuf[tid] + b2[0];
    }
}

// ---------------------------------------------------------------------------
// done_logits: 4 molecules per block, fp32
// ---------------------------------------------------------------------------
__global__ __launch_bounds__(256) void done_kernel(
    const float* __restrict__ hm, const float* __restrict__ W1,
    const float* __restrict__ b1, const float* __restrict__ W2,
    const float* __restrict__ b2, float* __restrict__ outD, int NM)
{
    __shared__ float rsh[4][256];
    __shared__ float red[4][4];
    const int tid = threadIdx.x;
    const int wv = tid >> 6, lane = tid & 63;
    const int mol0 = blockIdx.x * 4;
#pragma unroll
    for (int q = 0; q < 4; ++q)
        rsh[q][tid] = (mol0 + q < NM) ? hm[(size_t)(mol0 + q) * 256 + tid] : 0.f;
    __syncthreads();
    float h[4][2];
#pragma unroll
    for (int q = 0; q < 4; ++q) { h[q][0] = 0.f; h[q][1] = 0.f; }
    for (int k = 0; k < 256; ++k) {
        float w0 = W1[k * 512 + tid];
        float w1 = W1[k * 512 + tid + 256];
#pragma unroll
        for (int q = 0; q < 4; ++q) {
            h[q][0] += rsh[q][k] * w0;
            h[q][1] += rsh[q][k] * w1;
        }
    }
    float bb0 = b1[tid], bb1v = b1[tid + 256];
    float ww0 = W2[tid], ww1 = W2[tid + 256];
#pragma unroll
    for (int q = 0; q < 4; ++q) {
        float p = fmaxf(h[q][0] + bb0, 0.f) * ww0 + fmaxf(h[q][1] + bb1v, 0.f) * ww1;
#pragma unroll
        for (int off = 1; off < 64; off <<= 1) p += __shfl_xor(p, off);
        if (lane == 0) red[q][wv] = p;
    }
    __syncthreads();
    if (tid < 4 && mol0 + tid < NM)
        outD[mol0 + tid] = red[tid][0] + red[tid][1] + red[tid][2] + red[tid][3] + b2[0];
}

// ---------------------------------------------------------------------------
extern "C" void kernel_launch(void* const* d_in, const int* in_sizes, int n_in,
                              void* d_out, int out_size, void* d_ws, size_t ws_size,
                              hipStream_t stream)
{
    const float* c_atom  = (const float*)d_in[0];
    const float* ha_prev = (const float*)d_in[1];
    const float* W_vv    = (const float*)d_in[2];
    const float* W_vc    = (const float*)d_in[3];
    const float* bW1     = (const float*)d_in[4];
    const float* bb1     = (const float*)d_in[5];
    const float* bW2     = (const float*)d_in[6];
    const float* bb2     = (const float*)d_in[7];
    const float* uW1     = (const float*)d_in[8];
    const float* ub1     = (const float*)d_in[9];
    const float* uW2     = (const float*)d_in[10];
    const float* ub2     = (const float*)d_in[11];
    const float* dW1     = (const float*)d_in[12];
    const float* db1     = (const float*)d_in[13];
    const float* dW2     = (const float*)d_in[14];
    const float* db2     = (const float*)d_in[15];
    const int* mol_id    = (const int*)d_in[16];
    const int* bidx      = (const int*)d_in[17];

    const int H = 256, BS = 5;
    const int NA = in_sizes[0] / H;
    const int NB = in_sizes[17] / 2;
    const int NM = out_size - NB * BS - NA;

    float* out  = (float*)d_out;
    float* outB = out;
    float* outU = out + (size_t)NB * BS;
    float* outD = outU + NA;

    char* ws = (char*)d_ws;
    size_t off = 0;
    unsigned short* haB = (unsigned short*)(ws + off);
    off += (size_t)NA * H * 2;            off = (off + 255) & ~(size_t)255;
    float* hm = (float*)(ws + off);
    off += (size_t)NM * H * 4;            off = (off + 255) & ~(size_t)255;
    unsigned short* WcT = (unsigned short*)(ws + off);
    off += (size_t)131072 * 2;            off = (off + 255) & ~(size_t)255;
    unsigned short* WgT = (unsigned short*)(ws + off);
    off += (size_t)393216 * 2;            off = (off + 255) & ~(size_t)255;
    unsigned char* G = (unsigned char*)(ws + off);
    size_t need_G = off + (size_t)NA * 1024;

    const bool hasG = ws_size >= need_G;

    hipMemsetAsync(hm, 0, (size_t)NM * H * 4, stream);
    conv_weights<<<2048, 256, 0, stream>>>(W_vv, W_vc, bW1, uW1, WcT, WgT);
    ha_kernel<<<(NA + 127) / 128, 512, 0, stream>>>(ha_prev, c_atom, WcT, haB, NA);

    if (hasG) {
        g_kernel<<<dim3((NA + 127) / 128, 3), 1024, 0, stream>>>(
            haB, WgT, mol_id, hm, G, outU, ub1, uW2, ub2, NA);
        bond_stream<<<2048, 256, 0, stream>>>(G, bidx, bb1, bW2, bb2, outB, NB, 2048 * 4);
    } else {
        hm_fallback<<<(NA * 64 + 255) / 256, 256, 0, stream>>>(haB, mol_id, hm, NA);
        bond_gemm<<<(NB + 63) / 64, 512, 0, stream>>>(haB, bidx, WgT, bb1, bW2, bb2, outB, NB);
        uni_kernel<<<(NA + 63) / 64, 512, 0, stream>>>(haB, WgT, ub1, uW2, ub2, outU, NA);
    }
    done_kernel<<<(NM + 3) / 4, 256, 0, stream>>>(hm, dW1, db1, dW2, db2, outD, NM);
}